// Round 3
// baseline (156.639 us; speedup 1.0000x reference)
//
#include <hip/hip_runtime.h>
#include <math.h>

#define IN_F   1024
#define OUT_F  1024
#define TASK_D 256
#define RANK   8
#define HID    64
// SCALING = ALPHA / RANK = 1.0 (identity)

__device__ __forceinline__ float gelu_exact(float v) {
    return 0.5f * v * (1.0f + erff(v * 0.70710678118654752f));
}

// ---------------------------------------------------------------------------
// Kernel 1: generate LoRA tables for all 4 tasks (unchanged — verified).
//   vec_a_t : [4][RANK][OUT_F]  (TRANSPOSED: a_t[t][r][o] = a[t][o][r])
//   vec_b   : [4][RANK][IN_F]   (natural Wb2 row order)
// ---------------------------------------------------------------------------
__global__ __launch_bounds__(256) void gen_kernel(
    const float* __restrict__ task_emb,
    const float* __restrict__ Wa1, const float* __restrict__ ba1,
    const float* __restrict__ Wa2, const float* __restrict__ ba2,
    const float* __restrict__ Wb1, const float* __restrict__ bb1,
    const float* __restrict__ Wb2, const float* __restrict__ bb2,
    float* __restrict__ vec_a_t, float* __restrict__ vec_b)
{
    const int gen = blockIdx.x >> 7;             // 0 -> a, 1 -> b
    const int blk = blockIdx.x & 127;
    const float* __restrict__ W1 = gen ? Wb1 : Wa1;
    const float* __restrict__ b1 = gen ? bb1 : ba1;
    const float* __restrict__ W2 = gen ? Wb2 : Wa2;
    const float* __restrict__ b2 = gen ? bb2 : ba2;

    __shared__ float hs[4][HID];
    {
        const int j = threadIdx.x >> 2;          // hidden unit 0..63
        const int t = threadIdx.x & 3;           // task 0..3
        const float4* te = (const float4*)(task_emb + t * TASK_D);
        const float4* w  = (const float4*)(W1 + j * TASK_D);
        float acc = 0.f;
        #pragma unroll
        for (int d = 0; d < TASK_D / 4; ++d) {
            float4 a = te[d], b = w[d];
            acc += a.x * b.x + a.y * b.y + a.z * b.z + a.w * b.w;
        }
        hs[t][j] = gelu_exact(acc + b1[j]);
    }
    __syncthreads();

    const int lrow = threadIdx.x >> 2;           // 0..63  (W2 row within block)
    const int q    = threadIdx.x & 3;            // quarter of the 64 hidden dims
    const int o    = blk * 64 + lrow;            // W2 row 0..8191

    const float4* w2 = (const float4*)(W2 + (size_t)o * HID + q * 16);
    float acc0 = 0.f, acc1 = 0.f, acc2 = 0.f, acc3 = 0.f;
    #pragma unroll
    for (int k = 0; k < 4; ++k) {
        float4 w = w2[k];
        const int kb = q * 16 + k * 4;
        acc0 += hs[0][kb] * w.x + hs[0][kb+1] * w.y + hs[0][kb+2] * w.z + hs[0][kb+3] * w.w;
        acc1 += hs[1][kb] * w.x + hs[1][kb+1] * w.y + hs[1][kb+2] * w.z + hs[1][kb+3] * w.w;
        acc2 += hs[2][kb] * w.x + hs[2][kb+1] * w.y + hs[2][kb+2] * w.z + hs[2][kb+3] * w.w;
        acc3 += hs[3][kb] * w.x + hs[3][kb+1] * w.y + hs[3][kb+2] * w.z + hs[3][kb+3] * w.w;
    }
    #pragma unroll
    for (int off = 1; off <= 2; off <<= 1) {
        acc0 += __shfl_xor(acc0, off, 64);
        acc1 += __shfl_xor(acc1, off, 64);
        acc2 += __shfl_xor(acc2, off, 64);
        acc3 += __shfl_xor(acc3, off, 64);
    }
    if (q == 0) {
        const float bb = b2[o];
        float v[4] = { acc0 + bb, acc1 + bb, acc2 + bb, acc3 + bb };
        if (gen == 0) {
            const int oo = o >> 3, r = o & 7;    // vec_a row o -> (out oo, rank r)
            #pragma unroll
            for (int t = 0; t < 4; ++t)
                vec_a_t[t * (RANK * OUT_F) + r * OUT_F + oo] = v[t];
        } else {
            #pragma unroll
            for (int t = 0; t < 4; ++t)
                vec_b[t * (RANK * IN_F) + o] = v[t];
        }
    }
}

// ---------------------------------------------------------------------------
// Kernel 2 (v3): fused LoRA apply — zero LDS, one row per 64-lane wave.
// Grid = b_eff/4 = 2048 blocks x 4 waves = 8192 waves = 32 waves/CU (max).
// All 4 HBM x-loads (and later all 4 base_out loads) hoisted up front so
// each wave keeps 4 HBM loads in flight (128 KB/CU in flight at 32 waves ->
// covers ~900-cycle HBM latency at the CU's ~25 GB/s HBM share).
// b/a tables (32 KB/task) are L1/L2-resident, read 1 KB/instr coalesced.
// __launch_bounds__(256,8) caps VGPR at 64 so 8 waves/SIMD actually fit.
// ---------------------------------------------------------------------------
__global__ __launch_bounds__(256, 8) void apply_kernel(
    const float* __restrict__ x, const float* __restrict__ base_out,
    const float* __restrict__ vec_a_t, const float* __restrict__ vec_b,
    float* __restrict__ out, int g_per_task)
{
    const int t    = blockIdx.x / g_per_task;    // task 0..3
    const int g    = blockIdx.x % g_per_task;    // group within task
    const int wave = threadIdx.x >> 6;
    const int ln   = threadIdx.x & 63;

    const int j   = g * 4 + wave;                // within-task row index
    const int row = t + 4 * j;                   // global row

    const float* __restrict__ xr = x + (size_t)row * IN_F;
    const float* __restrict__ bt = vec_b + (size_t)t * (RANK * IN_F);

    // ---- phase 1: tmp[r] = x[row] . b[t][r] ------------------------------
    float4 xv[4];
    #pragma unroll
    for (int c = 0; c < 4; ++c)
        xv[c] = *(const float4*)(xr + c * 256 + ln * 4);

    float acc[RANK];
    #pragma unroll
    for (int r = 0; r < RANK; ++r) acc[r] = 0.f;

    #pragma unroll
    for (int c = 0; c < 4; ++c) {
        const int k = c * 256 + ln * 4;
        #pragma unroll
        for (int r = 0; r < RANK; ++r) {
            const float4 bv = *(const float4*)(bt + r * IN_F + k);
            acc[r] += xv[c].x * bv.x + xv[c].y * bv.y + xv[c].z * bv.z + xv[c].w * bv.w;
        }
    }

    // 64-lane butterfly; result broadcast to all lanes.
    #pragma unroll
    for (int off = 1; off <= 32; off <<= 1) {
        #pragma unroll
        for (int r = 0; r < RANK; ++r)
            acc[r] += __shfl_xor(acc[r], off, 64);
    }

    // ---- phase 2: out[row] = base_out[row] + sum_r tmp[r] * a_t[t][r] ----
    const float* __restrict__ at = vec_a_t + (size_t)t * (RANK * OUT_F);
    const float* __restrict__ br = base_out + (size_t)row * OUT_F;
    float* __restrict__ orow = out + (size_t)row * OUT_F;

    float4 bo[4];
    #pragma unroll
    for (int c = 0; c < 4; ++c)
        bo[c] = *(const float4*)(br + c * 256 + ln * 4);

    #pragma unroll
    for (int c = 0; c < 4; ++c) {
        const int o = c * 256 + ln * 4;
        float4 rv = bo[c];
        #pragma unroll
        for (int r = 0; r < RANK; ++r) {
            const float4 af = *(const float4*)(at + r * OUT_F + o);
            rv.x += acc[r] * af.x;
            rv.y += acc[r] * af.y;
            rv.z += acc[r] * af.z;
            rv.w += acc[r] * af.w;
        }
        *(float4*)(orow + o) = rv;
    }
}

extern "C" void kernel_launch(void* const* d_in, const int* in_sizes, int n_in,
                              void* d_out, int out_size, void* d_ws, size_t ws_size,
                              hipStream_t stream) {
    const float* x        = (const float*)d_in[0];
    const float* base_out = (const float*)d_in[1];
    const float* task_emb = (const float*)d_in[2];
    const float* Wa1      = (const float*)d_in[3];
    const float* ba1      = (const float*)d_in[4];
    const float* Wa2      = (const float*)d_in[5];
    const float* ba2      = (const float*)d_in[6];
    const float* Wb1      = (const float*)d_in[7];
    const float* bb1      = (const float*)d_in[8];
    const float* Wb2      = (const float*)d_in[9];
    const float* bb2      = (const float*)d_in[10];
    float* out = (float*)d_out;

    float* vec_a_t = (float*)d_ws;                        // 4*8192 floats
    float* vec_b   = vec_a_t + 4 * RANK * OUT_F;          // 4*8192 floats

    const int b_eff = in_sizes[0] / IN_F;                 // 8192

    gen_kernel<<<256, 256, 0, stream>>>(task_emb, Wa1, ba1, Wa2, ba2,
                                        Wb1, bb1, Wb2, bb2, vec_a_t, vec_b);

    const int nblk = b_eff / 4;                           // 4 rows per block
    apply_kernel<<<nblk, 256, 0, stream>>>(x, base_out, vec_a_t, vec_b, out,
                                           nblk / 4);
}

// Round 4
// 143.621 us; speedup vs baseline: 1.0906x; 1.0906x over previous
//
#include <hip/hip_runtime.h>
#include <math.h>

#define IN_F   1024
#define OUT_F  1024
#define TASK_D 256
#define RANK   8
#define HID    64
// SCALING = ALPHA / RANK = 1.0 (identity)

__device__ __forceinline__ float gelu_exact(float v) {
    return 0.5f * v * (1.0f + erff(v * 0.70710678118654752f));
}

// ---------------------------------------------------------------------------
// Kernel 1: generate LoRA tables for all 4 tasks (unchanged — verified).
//   vec_a_t : [4][RANK][OUT_F]  (TRANSPOSED: a_t[t][r][o] = a[t][o][r])
//   vec_b   : [4][RANK][IN_F]   (natural Wb2 row order)
// ---------------------------------------------------------------------------
__global__ __launch_bounds__(256) void gen_kernel(
    const float* __restrict__ task_emb,
    const float* __restrict__ Wa1, const float* __restrict__ ba1,
    const float* __restrict__ Wa2, const float* __restrict__ ba2,
    const float* __restrict__ Wb1, const float* __restrict__ bb1,
    const float* __restrict__ Wb2, const float* __restrict__ bb2,
    float* __restrict__ vec_a_t, float* __restrict__ vec_b)
{
    const int gen = blockIdx.x >> 7;             // 0 -> a, 1 -> b
    const int blk = blockIdx.x & 127;
    const float* __restrict__ W1 = gen ? Wb1 : Wa1;
    const float* __restrict__ b1 = gen ? bb1 : ba1;
    const float* __restrict__ W2 = gen ? Wb2 : Wa2;
    const float* __restrict__ b2 = gen ? bb2 : ba2;

    __shared__ float hs[4][HID];
    {
        const int j = threadIdx.x >> 2;          // hidden unit 0..63
        const int t = threadIdx.x & 3;           // task 0..3
        const float4* te = (const float4*)(task_emb + t * TASK_D);
        const float4* w  = (const float4*)(W1 + j * TASK_D);
        float acc = 0.f;
        #pragma unroll
        for (int d = 0; d < TASK_D / 4; ++d) {
            float4 a = te[d], b = w[d];
            acc += a.x * b.x + a.y * b.y + a.z * b.z + a.w * b.w;
        }
        hs[t][j] = gelu_exact(acc + b1[j]);
    }
    __syncthreads();

    const int lrow = threadIdx.x >> 2;           // 0..63  (W2 row within block)
    const int q    = threadIdx.x & 3;            // quarter of the 64 hidden dims
    const int o    = blk * 64 + lrow;            // W2 row 0..8191

    const float4* w2 = (const float4*)(W2 + (size_t)o * HID + q * 16);
    float acc0 = 0.f, acc1 = 0.f, acc2 = 0.f, acc3 = 0.f;
    #pragma unroll
    for (int k = 0; k < 4; ++k) {
        float4 w = w2[k];
        const int kb = q * 16 + k * 4;
        acc0 += hs[0][kb] * w.x + hs[0][kb+1] * w.y + hs[0][kb+2] * w.z + hs[0][kb+3] * w.w;
        acc1 += hs[1][kb] * w.x + hs[1][kb+1] * w.y + hs[1][kb+2] * w.z + hs[1][kb+3] * w.w;
        acc2 += hs[2][kb] * w.x + hs[2][kb+1] * w.y + hs[2][kb+2] * w.z + hs[2][kb+3] * w.w;
        acc3 += hs[3][kb] * w.x + hs[3][kb+1] * w.y + hs[3][kb+2] * w.z + hs[3][kb+3] * w.w;
    }
    #pragma unroll
    for (int off = 1; off <= 2; off <<= 1) {
        acc0 += __shfl_xor(acc0, off, 64);
        acc1 += __shfl_xor(acc1, off, 64);
        acc2 += __shfl_xor(acc2, off, 64);
        acc3 += __shfl_xor(acc3, off, 64);
    }
    if (q == 0) {
        const float bb = b2[o];
        float v[4] = { acc0 + bb, acc1 + bb, acc2 + bb, acc3 + bb };
        if (gen == 0) {
            const int oo = o >> 3, r = o & 7;    // vec_a row o -> (out oo, rank r)
            #pragma unroll
            for (int t = 0; t < 4; ++t)
                vec_a_t[t * (RANK * OUT_F) + r * OUT_F + oo] = v[t];
        } else {
            #pragma unroll
            for (int t = 0; t < 4; ++t)
                vec_b[t * (RANK * IN_F) + o] = v[t];
        }
    }
}

// ---------------------------------------------------------------------------
// Kernel 2 (v4): register-resident tables, 4 rows per wave.
// One wave = one task's b-table in 128 VGPRs (8r x 4 float4/lane), dots 4
// rows (x loads hoisted 2 rows at a time for MLP), butterfly-reduces to
// tmp[4][8]; then RELOADS the same 128 registers with the a-table and
// finishes the 4 rows (base_out hoisted 2 rows at a time).
// Table VMEM drops 64/row -> 16/row; stream VMEM 12/row.
// Grid = b_eff/16 = 512 blocks x 4 waves = 2048 waves; __launch_bounds__
// (256,2) -> VGPR<=256 (est ~220) -> 8 waves/CU -> whole grid co-resident.
// Blocks are task-pure: block b -> task b/128.
// ---------------------------------------------------------------------------
__global__ __launch_bounds__(256, 2) void apply_kernel(
    const float* __restrict__ x, const float* __restrict__ base_out,
    const float* __restrict__ vec_a_t, const float* __restrict__ vec_b,
    float* __restrict__ out, int waves_per_task)
{
    const int wave = threadIdx.x >> 6;
    const int ln   = threadIdx.x & 63;
    const int gw   = blockIdx.x * 4 + wave;      // global wave id
    const int t    = gw / waves_per_task;        // task 0..3
    const int u    = gw % waves_per_task;        // wave within task

    // ---- load b-table into registers -------------------------------------
    const float* __restrict__ bt = vec_b + (size_t)t * (RANK * IN_F);
    float4 tb[RANK][4];
    #pragma unroll
    for (int r = 0; r < RANK; ++r)
        #pragma unroll
        for (int c = 0; c < 4; ++c)
            tb[r][c] = *(const float4*)(bt + r * IN_F + c * 256 + ln * 4);

    float tmp[4][RANK];

    // ---- phase 1: tmp[i][r] = x[row_i] . b[t][r], 2-row hoisted chunks ---
    #pragma unroll
    for (int ii = 0; ii < 2; ++ii) {
        float4 xv[2][4];
        #pragma unroll
        for (int i = 0; i < 2; ++i) {
            const int row = t + 4 * (u * 4 + ii * 2 + i);
            const float* __restrict__ xr = x + (size_t)row * IN_F;
            #pragma unroll
            for (int c = 0; c < 4; ++c)
                xv[i][c] = *(const float4*)(xr + c * 256 + ln * 4);
        }
        #pragma unroll
        for (int i = 0; i < 2; ++i) {
            float acc[RANK];
            #pragma unroll
            for (int r = 0; r < RANK; ++r) acc[r] = 0.f;
            #pragma unroll
            for (int c = 0; c < 4; ++c) {
                #pragma unroll
                for (int r = 0; r < RANK; ++r) {
                    const float4 bv = tb[r][c];
                    acc[r] += xv[i][c].x * bv.x + xv[i][c].y * bv.y
                            + xv[i][c].z * bv.z + xv[i][c].w * bv.w;
                }
            }
            #pragma unroll
            for (int off = 1; off <= 32; off <<= 1) {
                #pragma unroll
                for (int r = 0; r < RANK; ++r)
                    acc[r] += __shfl_xor(acc[r], off, 64);
            }
            #pragma unroll
            for (int r = 0; r < RANK; ++r) tmp[ii * 2 + i][r] = acc[r];
        }
    }

    // ---- swap table registers to a ---------------------------------------
    const float* __restrict__ at = vec_a_t + (size_t)t * (RANK * OUT_F);
    #pragma unroll
    for (int r = 0; r < RANK; ++r)
        #pragma unroll
        for (int c = 0; c < 4; ++c)
            tb[r][c] = *(const float4*)(at + r * OUT_F + c * 256 + ln * 4);

    // ---- phase 2: out[row] = base_out[row] + sum_r tmp[r]*a_t[r] ---------
    #pragma unroll
    for (int ii = 0; ii < 2; ++ii) {
        float4 bo[2][4];
        #pragma unroll
        for (int i = 0; i < 2; ++i) {
            const int row = t + 4 * (u * 4 + ii * 2 + i);
            const float* __restrict__ br = base_out + (size_t)row * OUT_F;
            #pragma unroll
            for (int c = 0; c < 4; ++c)
                bo[i][c] = *(const float4*)(br + c * 256 + ln * 4);
        }
        #pragma unroll
        for (int i = 0; i < 2; ++i) {
            const int row = t + 4 * (u * 4 + ii * 2 + i);
            float* __restrict__ orow = out + (size_t)row * OUT_F;
            #pragma unroll
            for (int c = 0; c < 4; ++c) {
                float4 rv = bo[i][c];
                #pragma unroll
                for (int r = 0; r < RANK; ++r) {
                    const float4 af = tb[r][c];
                    const float s = tmp[ii * 2 + i][r];
                    rv.x += s * af.x;
                    rv.y += s * af.y;
                    rv.z += s * af.z;
                    rv.w += s * af.w;
                }
                *(float4*)(orow + c * 256 + ln * 4) = rv;
            }
        }
    }
}

extern "C" void kernel_launch(void* const* d_in, const int* in_sizes, int n_in,
                              void* d_out, int out_size, void* d_ws, size_t ws_size,
                              hipStream_t stream) {
    const float* x        = (const float*)d_in[0];
    const float* base_out = (const float*)d_in[1];
    const float* task_emb = (const float*)d_in[2];
    const float* Wa1      = (const float*)d_in[3];
    const float* ba1      = (const float*)d_in[4];
    const float* Wa2      = (const float*)d_in[5];
    const float* ba2      = (const float*)d_in[6];
    const float* Wb1      = (const float*)d_in[7];
    const float* bb1      = (const float*)d_in[8];
    const float* Wb2      = (const float*)d_in[9];
    const float* bb2      = (const float*)d_in[10];
    float* out = (float*)d_out;

    float* vec_a_t = (float*)d_ws;                        // 4*8192 floats
    float* vec_b   = vec_a_t + 4 * RANK * OUT_F;          // 4*8192 floats

    const int b_eff = in_sizes[0] / IN_F;                 // 8192

    gen_kernel<<<256, 256, 0, stream>>>(task_emb, Wa1, ba1, Wa2, ba2,
                                        Wb1, bb1, Wb2, bb2, vec_a_t, vec_b);

    const int nblk = b_eff / 16;                          // 16 rows per block
    apply_kernel<<<nblk, 256, 0, stream>>>(x, base_out, vec_a_t, vec_b, out,
                                           nblk);         // waves_per_task = nblk
}